// Round 9
// baseline (343.348 us; speedup 1.0000x reference)
//
#include <hip/hip_runtime.h>
#include <hip/hip_bf16.h>

#define DIMF 128
#define KNBR 32
#define NH 4
#define DH 32
#define RADIUS 0.3f
#define CB 8       // centers per attn block (2 per wave)
#define CAND 256   // max candidates/center (Poisson max lambda~118)
#define PPB 32     // points per argmin block

#define PACK_BLOCKS 172    // 12 tr4-equivalents + 16 Wk + 64 xyz4 + 16 cds4 + 32 w1h + 32 w2h

typedef unsigned long long u64t;
typedef _Float16 f16x8 __attribute__((ext_vector_type(8)));
typedef _Float16 f16x4 __attribute__((ext_vector_type(4)));
typedef float f32x4 __attribute__((ext_vector_type(4)));

// float4-granular transpose tile: out4[a*BI + b] = in4[b*AI + a]
__device__ __forceinline__ void tr4_tile(const float4* __restrict__ in4, float4* __restrict__ out4,
                                         int AI, int BI, int a0, int b0, int t, char* smem) {
    float4(*tile)[33] = (float4(*)[33])smem;
    int tx = t & 31, ty = t >> 5;  // 32 x 8
    for (int r = ty; r < 32; r += 8) tile[r][tx] = in4[(long)(b0 + r) * AI + a0 + tx];
    __syncthreads();
    for (int r = ty; r < 32; r += 8) out4[(long)(a0 + r) * BI + b0 + tx] = tile[tx][r];
}

// ====== kernel 1: weight packs + xyz4/cds4 + f16 MFMA weight packs (R6) =====
__global__ __launch_bounds__(256) void pack_kernel(
    const float* __restrict__ xyz, const int* __restrict__ idxc,
    const float* __restrict__ Wq, const float* __restrict__ Wv,
    const float* __restrict__ Wo, const float* __restrict__ W1,
    const float* __restrict__ W2, const float* __restrict__ Wk,
    float4* __restrict__ qp4, float4* __restrict__ vp4, float4* __restrict__ op4,
    float4* __restrict__ kp4, f16x8* __restrict__ w1h, f16x8* __restrict__ w2h,
    float4* __restrict__ xyz4, float4* __restrict__ cds4, int N, int M) {
    __shared__ __align__(16) char smem[16896];
    int pk = blockIdx.x, t = threadIdx.x;
    if (pk < 4) {
        tr4_tile((const float4*)Wq, qp4, 32, 128, 0, pk * 32, t, smem);
    } else if (pk < 8) {
        tr4_tile((const float4*)Wv, vp4, 32, 128, 0, (pk - 4) * 32, t, smem);
    } else if (pk < 12) {
        tr4_tile((const float4*)Wo, op4, 32, 128, 0, (pk - 8) * 32, t, smem);
    } else if (pk < 28) {
        // Wk pack: kp4[q*128+j] = {Wk[(4q+r)*128+j]}_{r=0..3}
        int idx = (pk - 12) * 256 + t;
        int q = idx >> 7, j = idx & 127;
        float4 w;
        w.x = Wk[(long)(4 * q + 0) * DIMF + j];
        w.y = Wk[(long)(4 * q + 1) * DIMF + j];
        w.z = Wk[(long)(4 * q + 2) * DIMF + j];
        w.w = Wk[(long)(4 * q + 3) * DIMF + j];
        kp4[q * DIMF + j] = w;
    } else if (pk < 92) {
        int idx = (pk - 28) * 256 + t;
        if (idx < N) {
            float x = xyz[3 * idx], y = xyz[3 * idx + 1], z = xyz[3 * idx + 2];
            xyz4[idx] = make_float4(x, y, z, (x * x + y * y) + z * z);
        }
    } else if (pk < 108) {
        int idx = (pk - 92) * 256 + t;
        if (idx < M) {
            int ic = idxc[idx];
            float cx = xyz[3 * ic], cy = xyz[3 * ic + 1], cz = xyz[3 * ic + 2];
            cds4[idx] = make_float4(-2.0f * cx, -2.0f * cy, -2.0f * cz,
                                    (cx * cx + cy * cy) + cz * cz);
        }
    } else if (pk < 140) {
        // w1h: B-frags of W1^T [128 x 512]; nt(32) x ks(4) x lane(64)
        int e = (pk - 108) * 256 + t;
        int l = e & 63, ks = (e >> 6) & 3, nt = e >> 8;
        int row = nt * 16 + (l & 15);
        int cb = ks * 32 + (l >> 4) * 8;
        const float* src = W1 + (long)row * DIMF + cb;
        f16x8 v;
#pragma unroll
        for (int j = 0; j < 8; ++j) v[j] = (_Float16)src[j];
        w1h[e] = v;
    } else {
        // w2h: B-frags of W2^T [512 x 128]; nt(8) x ks(16) x lane(64)
        int e = (pk - 140) * 256 + t;
        int l = e & 63, ks = (e >> 6) & 15, nt = e >> 10;
        int row = nt * 16 + (l & 15);
        int cb = ks * 32 + (l >> 4) * 8;
        const float* src = W2 + (long)row * (4 * DIMF) + cb;
        f16x8 v;
#pragma unroll
        for (int j = 0; j < 8; ++j) v[j] = (_Float16)src[j];
        w2h[e] = v;
    }
}

// ================= kernel 2: main — per-wave barrier-free attn ==============
// R6 post-mortem: ~27us of issue in a 100us kernel, no pipe saturated -> the
// ~15 block-wide barriers lockstep 4 waves so all stalls correlate. This maps
// phases A..G so each WAVE owns 2 centers end-to-end: producer==consumer wave,
// wave-lockstep makes LDS RAW free, zero barriers cf-load..LN1. Only the
// block-cooperative MFMA FFN (H/I, R6-proven) keeps barriers (6 total vs 15).
// LDS 54.3KB total -> 3 blocks/CU, waves decorrelate into independent streams.
//
// LDS map (bytes):
//   0      qw/pool f32 [4 waves][2][512] (16K)  <- cand[8][256] u64 overlay
//   16384  cf  f32 [4][2][128] (4K)             <- S3out f32 [8][128] overlay
//   20480  q/updin f32 [4][2][128] (4K)
//   24576  sm/upd  f32 [4][2][128] (4K)
//   28672  cf2 f32 [4][2][128] (4K)
//   32768  cf2h f16 [16][128] swizzled (4K)
//   36864  hid  f16 [16][512] swizzled (16K)
__global__ __launch_bounds__(256) void main_kernel(
    const float4* __restrict__ xyz4, const float4* __restrict__ cds4g,
    const float* __restrict__ feats, const int* __restrict__ idxc,
    const float4* __restrict__ qp4, const float4* __restrict__ kp4,
    const float4* __restrict__ vp4, const float4* __restrict__ op4,
    const float* __restrict__ bo, const float* __restrict__ g1,
    const float* __restrict__ be1, const float* __restrict__ g2,
    const float* __restrict__ be2, const f16x8* __restrict__ w1h,
    const float* __restrict__ b1f, const f16x8* __restrict__ w2h,
    const float* __restrict__ b2f, float* __restrict__ cfin,
    int* __restrict__ bestm, int N, int M) {
    __shared__ __align__(16) char smem[53248];
    __shared__ int nbrl[CB][KNBR];
    __shared__ int cnt[CB];

    int t = threadIdx.x;
    int b = blockIdx.x;
    int nAttn = M / CB;

    if (b >= nAttn) {
        // ---------- nearest-center argmin, 32 pts/block, 8 lanes/pt ----------
        float4* cds = (float4*)smem;
        int pt = t >> 3, q = t & 7;
        int n = (b - nAttn) * PPB + pt;
        float4 p4 = xyz4[n];
        float px = p4.x, py = p4.y, pz = p4.z;
        float bd0 = INFINITY, bd1 = INFINITY;
        int bm0 = 0, bm1 = 0;
        for (int c0 = 0; c0 < M; c0 += 1024) {
            __syncthreads();
            for (int i = t; i < 1024; i += 256) cds[i] = cds4g[c0 + i];
            __syncthreads();
#pragma unroll 8
            for (int i = 0; i < 64; ++i) {
                int ci0 = q + (2 * i) * 8, ci1 = q + (2 * i + 1) * 8;
                float4 ca = cds[ci0];
                float4 cb = cds[ci1];
                float sa = fmaf(ca.x, px, fmaf(ca.y, py, fmaf(ca.z, pz, ca.w)));
                float sb = fmaf(cb.x, px, fmaf(cb.y, py, fmaf(cb.z, pz, cb.w)));
                if (sa < bd0) { bd0 = sa; bm0 = c0 + ci0; }
                if (sb < bd1) { bd1 = sb; bm1 = c0 + ci1; }
            }
        }
        if (bd1 < bd0 || (bd1 == bd0 && bm1 < bm0)) { bd0 = bd1; bm0 = bm1; }
#pragma unroll
        for (int o = 1; o < 8; o <<= 1) {
            float obd = __shfl_xor(bd0, o);
            int obm = __shfl_xor(bm0, o);
            if (obd < bd0 || (obd == bd0 && obm < bm0)) { bd0 = obd; bm0 = obm; }
        }
        if (q == 0) bestm[n] = bm0;
        return;
    }

    int m0 = b * CB;

    // ======== phase 1: radius top-K for centers m0..m0+7 (R6 verbatim) =====
    {
        u64t(*cand)[CAND] = (u64t(*)[CAND])smem;
        if (t < CB) cnt[t] = 0;
        __syncthreads();
        float nx[CB], ny[CB], nz[CB], cw[CB];
#pragma unroll
        for (int tc = 0; tc < CB; ++tc) {
            float4 c4v = cds4g[m0 + tc];
            nx[tc] = c4v.x; ny[tc] = c4v.y; nz[tc] = c4v.z; cw[tc] = c4v.w;
        }
        const float R2 = RADIUS * RADIUS;
        for (int n = t; n < N; n += 256) {
            float4 p4 = xyz4[n];
            float rhs = R2 - p4.w;
#pragma unroll
            for (int tc = 0; tc < CB; ++tc) {
                float s = fmaf(nx[tc], p4.x, fmaf(ny[tc], p4.y, fmaf(nz[tc], p4.z, cw[tc])));
                if (s < rhs) {
                    int pos = atomicAdd(&cnt[tc], 1);
                    if (pos < CAND)
                        cand[tc][pos] = (((u64t)__float_as_uint(fmaxf(s + p4.w, 0.0f))) << 32) | (unsigned)n;
                }
            }
        }
        __syncthreads();
        int wv = t >> 6, lane = t & 63;
        for (int rep = 0; rep < 2; ++rep) {
            int cidx = wv + rep * 4;
            int C = cnt[cidx] < CAND ? cnt[cidx] : CAND;
            const u64t* vc = cand[cidx];
            if (C <= 64) {
                u64t mykey = (lane < C) ? vc[lane] : ~0ull;
                int rank = 0;
                for (int j = 0; j < C; ++j) rank += (vc[j] < mykey) ? 1 : 0;
                if (lane < C && rank < KNBR) nbrl[cidx][rank] = (int)(mykey & 0xffffffffu);
                if (lane >= C && lane < KNBR) nbrl[cidx][lane] = -1;
            } else {
                u64t mykey[4];
                int myrank[4];
#pragma unroll
                for (int s = 0; s < 4; ++s) {
                    int i = s * 64 + lane;
                    mykey[s] = (i < C) ? vc[i] : ~0ull;
                    myrank[s] = 0;
                }
                for (int j = 0; j < C; ++j) {
                    u64t kj = vc[j];
#pragma unroll
                    for (int s = 0; s < 4; ++s) myrank[s] += (kj < mykey[s]) ? 1 : 0;
                }
#pragma unroll
                for (int s = 0; s < 4; ++s) {
                    int i = s * 64 + lane;
                    if (i < C && myrank[s] < KNBR) nbrl[cidx][myrank[s]] = (int)(mykey[s] & 0xffffffffu);
                }
            }
        }
    }
    __syncthreads();  // cand reads done; smem becomes attn buffers

    // ======== phase 2: attention, per-wave (wave w owns centers 2w, 2w+1) ==
    int w = t >> 6, lane = t & 63;
    float* qwp = (float*)(smem) + w * 1024;           // [2][512] qw -> pool
    float* cfw = (float*)(smem + 16384) + w * 256;    // [2][128] cf
    float* qb = (float*)(smem + 20480) + w * 256;     // [2][128] q -> updin
    float* smu = (float*)(smem + 24576) + w * 256;    // [2][128] sm -> upd
    float* cf2w = (float*)(smem + 28672) + w * 256;   // [2][128] cf2
    float* S3out = (float*)(smem + 16384);            // [8][128] FFN out (cf dead)

    int cl = lane >> 5, l31 = lane & 31;
    int crow = 2 * w + cl;

    // cf load: lane -> (center cl, float4 l31)
    {
        int ic = idxc[m0 + crow];
        *(float4*)(cfw + cl * 128 + l31 * 4) = *(const float4*)&feats[(long)ic * DIMF + l31 * 4];
    }

    // ---- A: q = Wq @ cf (scaled) -> qb ----
#pragma unroll
    for (int c = 0; c < 2; ++c) {
        float acc0 = 0.f, acc1 = 0.f;
        const float4* cf4 = (const float4*)(cfw + c * 128);
        for (int jj = 0; jj < 32; ++jj) {
            float4 x = cf4[jj];
            float4 w0 = qp4[jj * DIMF + lane];
            float4 w1 = qp4[jj * DIMF + lane + 64];
            acc0 += w0.x * x.x + w0.y * x.y + w0.z * x.z + w0.w * x.w;
            acc1 += w1.x * x.x + w1.y * x.y + w1.z * x.z + w1.w * x.w;
        }
        qb[c * 128 + lane] = acc0 * 0.17677669529663687f;
        qb[c * 128 + lane + 64] = acc1 * 0.17677669529663687f;
    }

    // ---- B: qw[c][h][j] -> qwp ----
#pragma unroll
    for (int c = 0; c < 2; ++c) {
#pragma unroll
        for (int h = 0; h < NH; ++h) {
            float a0 = 0.f, a1 = 0.f;
#pragma unroll
            for (int d4 = 0; d4 < 8; ++d4) {
                float4 qv = *(const float4*)(qb + c * 128 + h * DH + d4 * 4);
                float4 w0 = kp4[(h * 8 + d4) * DIMF + lane];
                float4 w1 = kp4[(h * 8 + d4) * DIMF + lane + 64];
                a0 += qv.x * w0.x + qv.y * w0.y + qv.z * w0.z + qv.w * w0.w;
                a1 += qv.x * w1.x + qv.y * w1.y + qv.z * w1.z + qv.w * w1.w;
            }
            qwp[c * 512 + h * DIMF + lane] = a0;
            qwp[c * 512 + h * DIMF + lane + 64] = a1;
        }
    }

    // ---- C: logits + softmax -> smu ----
    {
        int ni = nbrl[crow][l31];
        const float* nrow = feats + (long)(ni < 0 ? 0 : ni) * DIMF;
        float lg[4] = {0.f, 0.f, 0.f, 0.f};
        const float4* qw4 = (const float4*)(qwp + cl * 512);
        for (int jj = 0; jj < 32; ++jj) {
            float4 f = *(const float4*)&nrow[jj * 4];
#pragma unroll
            for (int h = 0; h < NH; ++h) {
                float4 qv = qw4[h * 32 + jj];
                lg[h] += f.x * qv.x + f.y * qv.y + f.z * qv.z + f.w * qv.w;
            }
        }
        if (ni < 0) { lg[0] = -1e9f; lg[1] = -1e9f; lg[2] = -1e9f; lg[3] = -1e9f; }
#pragma unroll
        for (int h = 0; h < NH; ++h) {
            float mx = lg[h];
            for (int o = 16; o; o >>= 1) mx = fmaxf(mx, __shfl_xor(mx, o, 32));
            float e = expf(lg[h] - mx);
            float s = e;
            for (int o = 16; o; o >>= 1) s += __shfl_xor(s, o, 32);
            smu[cl * 128 + h * KNBR + l31] = e / s;
        }
    }

    // ---- D: pool -> qwp (qw dead after C; wave-sequential, no barrier) ----
    {
        int j4 = l31 * 4;
        float a0x = 0.f, a0y = 0.f, a0z = 0.f, a0w = 0.f;
        float a1x = 0.f, a1y = 0.f, a1z = 0.f, a1w = 0.f;
        float a2x = 0.f, a2y = 0.f, a2z = 0.f, a2w = 0.f;
        float a3x = 0.f, a3y = 0.f, a3z = 0.f, a3w = 0.f;
        for (int k = 0; k < KNBR; ++k) {
            int ni = nbrl[crow][k];
            const float* nrow = feats + (long)(ni < 0 ? 0 : ni) * DIMF;
            float4 f = *(const float4*)&nrow[j4];
            float w0 = smu[cl * 128 + 0 * KNBR + k], w1 = smu[cl * 128 + 1 * KNBR + k];
            float w2 = smu[cl * 128 + 2 * KNBR + k], w3 = smu[cl * 128 + 3 * KNBR + k];
            a0x += w0 * f.x; a0y += w0 * f.y; a0z += w0 * f.z; a0w += w0 * f.w;
            a1x += w1 * f.x; a1y += w1 * f.y; a1z += w1 * f.z; a1w += w1 * f.w;
            a2x += w2 * f.x; a2y += w2 * f.y; a2z += w2 * f.z; a2w += w2 * f.w;
            a3x += w3 * f.x; a3y += w3 * f.y; a3z += w3 * f.z; a3w += w3 * f.w;
        }
        *(float4*)(qwp + cl * 512 + 0 * DIMF + j4) = make_float4(a0x, a0y, a0z, a0w);
        *(float4*)(qwp + cl * 512 + 1 * DIMF + j4) = make_float4(a1x, a1y, a1z, a1w);
        *(float4*)(qwp + cl * 512 + 2 * DIMF + j4) = make_float4(a2x, a2y, a2z, a2w);
        *(float4*)(qwp + cl * 512 + 3 * DIMF + j4) = make_float4(a3x, a3y, a3z, a3w);
    }

    // ---- E: updin -> qb (q dead after B) ----
#pragma unroll
    for (int c = 0; c < 2; ++c) {
#pragma unroll
        for (int r = 0; r < 2; ++r) {
            int i = lane + r * 64;
            int h = i >> 5, d = i & 31;
            float acc = 0.f;
            const float4* p4 = (const float4*)(qwp + c * 512 + h * DIMF);
            for (int jj = 0; jj < 32; ++jj) {
                float4 wv = vp4[jj * DIMF + i];
                float4 pv = p4[jj];
                acc += wv.x * pv.x + wv.y * pv.y + wv.z * pv.z + wv.w * pv.w;
            }
            qb[c * 128 + d * NH + h] = acc;
        }
    }

    // ---- F: upd = Wo @ updin + bo -> smu (sm dead after D) ----
#pragma unroll
    for (int c = 0; c < 2; ++c) {
#pragma unroll
        for (int r = 0; r < 2; ++r) {
            int i = lane + r * 64;
            float acc = 0.f;
            const float4* u4 = (const float4*)(qb + c * 128);
            for (int jj = 0; jj < 32; ++jj) {
                float4 wv = op4[jj * DIMF + i];
                float4 xv = u4[jj];
                acc += wv.x * xv.x + wv.y * xv.y + wv.z * xv.z + wv.w * xv.w;
            }
            smu[c * 128 + i] = acc + bo[i];
        }
    }

    // ---- G: LN1 + residual -> cf2w (f32) + cf2h (f16, swizzled) ----
    {
        int i4 = l31 * 4;
        float4 u = *(const float4*)(smu + cl * 128 + i4);
        float s = ((u.x + u.y) + u.z) + u.w;
        for (int o = 16; o; o >>= 1) s += __shfl_xor(s, o, 32);
        float mu = s * (1.0f / DIMF);
        float d0 = u.x - mu, d1 = u.y - mu, d2 = u.z - mu, d3 = u.w - mu;
        float vs = ((d0 * d0 + d1 * d1) + d2 * d2) + d3 * d3;
        for (int o = 16; o; o >>= 1) vs += __shfl_xor(vs, o, 32);
        float rs = 1.0f / sqrtf(vs * (1.0f / DIMF) + 1e-5f);
        float4 g = *(const float4*)&g1[i4];
        float4 bb = *(const float4*)&be1[i4];
        float4 base = *(const float4*)(cfw + cl * 128 + i4);
        float4 r;
        r.x = base.x + d0 * rs * g.x + bb.x;
        r.y = base.y + d1 * rs * g.y + bb.y;
        r.z = base.z + d2 * rs * g.z + bb.z;
        r.w = base.w + d3 * rs * g.w + bb.w;
        *(float4*)(cf2w + cl * 128 + i4) = r;
        int byteoff = (crow * 256 + i4 * 2) ^ ((crow & 7) << 4);
        f16x4 hv = {(_Float16)r.x, (_Float16)r.y, (_Float16)r.z, (_Float16)r.w};
        *(f16x4*)(smem + 32768 + byteoff) = hv;
    }
    __syncthreads();

    // ---- H: FFN1 via f16 MFMA (block-cooperative, R6 verbatim) ----
    {
        int la = lane & 15, kg = lane >> 4;
        f16x8 afr[4];
#pragma unroll
        for (int ks = 0; ks < 4; ++ks) {
            int byteoff = (la * 256 + ks * 64 + kg * 16) ^ ((la & 7) << 4);
            afr[ks] = *(const f16x8*)(smem + 32768 + byteoff);
        }
#pragma unroll
        for (int nt0 = 0; nt0 < 8; ++nt0) {
            int nt = w * 8 + nt0;
            f32x4 acc = {0.f, 0.f, 0.f, 0.f};
#pragma unroll
            for (int ks = 0; ks < 4; ++ks) {
                f16x8 bfr = w1h[(nt * 4 + ks) * 64 + lane];
                acc = __builtin_amdgcn_mfma_f32_16x16x32_f16(afr[ks], bfr, acc, 0, 0, 0);
            }
            int col = nt * 16 + la;
            float bb = b1f[col];
#pragma unroll
            for (int r = 0; r < 4; ++r) {
                int row = kg * 4 + r;
                float v = fmaxf(acc[r] + bb, 0.f);
                int byteoff = (row * 1024 + col * 2) ^ ((row & 7) << 4);
                *(_Float16*)(smem + 36864 + byteoff) = (_Float16)v;
            }
        }
    }
    __syncthreads();

    // ---- I: FFN2 via f16 MFMA -> S3out rows 0..7 (cf region, dead) ----
    {
        int la = lane & 15, kg = lane >> 4;
        int nt0 = w * 2, nt1 = w * 2 + 1;
        f32x4 acc0 = {0.f, 0.f, 0.f, 0.f}, acc1 = {0.f, 0.f, 0.f, 0.f};
#pragma unroll
        for (int ks = 0; ks < 16; ++ks) {
            int byteoff = (la * 1024 + ks * 64 + kg * 16) ^ ((la & 7) << 4);
            f16x8 afr = *(const f16x8*)(smem + 36864 + byteoff);
            f16x8 b0 = w2h[(nt0 * 16 + ks) * 64 + lane];
            f16x8 b1v = w2h[(nt1 * 16 + ks) * 64 + lane];
            acc0 = __builtin_amdgcn_mfma_f32_16x16x32_f16(afr, b0, acc0, 0, 0, 0);
            acc1 = __builtin_amdgcn_mfma_f32_16x16x32_f16(afr, b1v, acc1, 0, 0, 0);
        }
        if (lane < 32) {
            float bb0 = b2f[nt0 * 16 + la];
            float bb1 = b2f[nt1 * 16 + la];
#pragma unroll
            for (int r = 0; r < 4; ++r) {
                int row = kg * 4 + r;
                S3out[row * DIMF + nt0 * 16 + la] = acc0[r] + bb0;
                S3out[row * DIMF + nt1 * 16 + la] = acc1[r] + bb1;
            }
        }
    }
    __syncthreads();

    // ---- J: LN2 + residual -> cfin (per-wave) ----
    {
        int i4 = l31 * 4;
        float4 u = *(const float4*)(S3out + crow * DIMF + i4);
        float s = ((u.x + u.y) + u.z) + u.w;
        for (int o = 16; o; o >>= 1) s += __shfl_xor(s, o, 32);
        float mu = s * (1.0f / DIMF);
        float d0 = u.x - mu, d1 = u.y - mu, d2 = u.z - mu, d3 = u.w - mu;
        float vs = ((d0 * d0 + d1 * d1) + d2 * d2) + d3 * d3;
        for (int o = 16; o; o >>= 1) vs += __shfl_xor(vs, o, 32);
        float rs = 1.0f / sqrtf(vs * (1.0f / DIMF) + 1e-5f);
        float4 g = *(const float4*)&g2[i4];
        float4 bb = *(const float4*)&be2[i4];
        float4 base = *(const float4*)(cf2w + cl * 128 + i4);
        float4 r;
        r.x = base.x + d0 * rs * g.x + bb.x;
        r.y = base.y + d1 * rs * g.y + bb.y;
        r.z = base.z + d2 * rs * g.z + bb.z;
        r.w = base.w + d3 * rs * g.w + bb.w;
        *(float4*)&cfin[(long)(m0 + crow) * DIMF + i4] = r;
    }
}

// ================= kernel 3: out = feats + cfin[bestm] ======================
__global__ __launch_bounds__(256) void out_kernel(const float4* __restrict__ feats4,
                                                  const float* __restrict__ cfin,
                                                  const int* __restrict__ bestm,
                                                  float4* __restrict__ out4, int total) {
    int idx = blockIdx.x * 256 + threadIdx.x;
    if (idx >= total) return;
    int n = idx >> 5, c = idx & 31;
    const float4* cf4 = (const float4*)cfin;
    float4 f = feats4[idx];
    float4 g = cf4[(long)bestm[n] * 32 + c];
    out4[idx] = make_float4(f.x + g.x, f.y + g.y, f.z + g.z, f.w + g.w);
}

extern "C" void kernel_launch(void* const* d_in, const int* in_sizes, int n_in,
                              void* d_out, int out_size, void* d_ws, size_t ws_size,
                              hipStream_t stream) {
    const float* xyz = (const float*)d_in[0];
    const float* feats = (const float*)d_in[1];
    const int* idxc = (const int*)d_in[2];
    const float* Wq = (const float*)d_in[3];
    const float* Wk = (const float*)d_in[4];
    const float* Wv = (const float*)d_in[5];
    const float* Wo = (const float*)d_in[6];
    const float* bo = (const float*)d_in[7];
    const float* g1 = (const float*)d_in[8];
    const float* be1 = (const float*)d_in[9];
    const float* g2 = (const float*)d_in[10];
    const float* be2 = (const float*)d_in[11];
    const float* W1 = (const float*)d_in[12];
    const float* b1f = (const float*)d_in[13];
    const float* W2 = (const float*)d_in[14];
    const float* b2f = (const float*)d_in[15];

    int N = in_sizes[0] / 3;
    int M = in_sizes[2];

    char* ws = (char*)d_ws;
    size_t off = 0;
    float* cfin = (float*)(ws + off); off += (size_t)M * DIMF * 4;
    int* bestm = (int*)(ws + off); off += (size_t)N * 4;
    float4* qp4 = (float4*)(ws + off); off += (size_t)DIMF * DIMF * 4;
    float4* vp4 = (float4*)(ws + off); off += (size_t)DIMF * DIMF * 4;
    float4* op4 = (float4*)(ws + off); off += (size_t)DIMF * DIMF * 4;
    float4* kp4 = (float4*)(ws + off); off += (size_t)DIMF * DIMF * 4;
    f16x8* w1h = (f16x8*)(ws + off); off += (size_t)8192 * 16;
    f16x8* w2h = (f16x8*)(ws + off); off += (size_t)8192 * 16;
    float4* xyz4 = (float4*)(ws + off); off += (size_t)N * 16;
    float4* cds4 = (float4*)(ws + off); off += (size_t)M * 16;
    (void)ws_size; (void)n_in; (void)out_size;

    pack_kernel<<<PACK_BLOCKS, 256, 0, stream>>>(
        xyz, idxc, Wq, Wv, Wo, W1, W2, Wk,
        qp4, vp4, op4, kp4, w1h, w2h, xyz4, cds4, N, M);
    main_kernel<<<M / CB + N / PPB, 256, 0, stream>>>(
        xyz4, cds4, feats, idxc, qp4, kp4, vp4, op4, bo, g1, be1, g2, be2,
        w1h, b1f, w2h, b2f, cfin, bestm, N, M);
    out_kernel<<<(N * DIMF / 4 + 255) / 256, 256, 0, stream>>>(
        (const float4*)feats, cfin, bestm, (float4*)d_out, N * DIMF / 4);
}

// Round 10
// 174.282 us; speedup vs baseline: 1.9701x; 1.9701x over previous
//
#include <hip/hip_runtime.h>
#include <hip/hip_bf16.h>

#define DIMF 128
#define KNBR 32
#define NH 4
#define DH 32
#define RADIUS 0.3f
#define CB 8       // centers per attn block (R6 best-known structure)
#define CAND 256   // max candidates/center (Poisson max lambda~118)
#define PPB 32     // points per argmin block

#define PACK_BLOCKS 172    // 12 tr4 + 16 Wk + 64 xyz4 + 16 cds4 + 32 w1h + 32 w2h

typedef unsigned long long u64t;
typedef _Float16 f16x8 __attribute__((ext_vector_type(8)));
typedef _Float16 f16x4 __attribute__((ext_vector_type(4)));
typedef float f32x4 __attribute__((ext_vector_type(4)));

// float4-granular transpose tile: out4[a*BI + b] = in4[b*AI + a]
__device__ __forceinline__ void tr4_tile(const float4* __restrict__ in4, float4* __restrict__ out4,
                                         int AI, int BI, int a0, int b0, int t, char* smem) {
    float4(*tile)[33] = (float4(*)[33])smem;
    int tx = t & 31, ty = t >> 5;  // 32 x 8
    for (int r = ty; r < 32; r += 8) tile[r][tx] = in4[(long)(b0 + r) * AI + a0 + tx];
    __syncthreads();
    for (int r = ty; r < 32; r += 8) out4[(long)(a0 + r) * BI + b0 + tx] = tile[tx][r];
}

// ====== kernel 1: weight packs + xyz4/cds4 + f16 MFMA weight packs (R6) =====
__global__ __launch_bounds__(256) void pack_kernel(
    const float* __restrict__ xyz, const int* __restrict__ idxc,
    const float* __restrict__ Wq, const float* __restrict__ Wv,
    const float* __restrict__ Wo, const float* __restrict__ W1,
    const float* __restrict__ W2, const float* __restrict__ Wk,
    float4* __restrict__ qp4, float4* __restrict__ vp4, float4* __restrict__ op4,
    float4* __restrict__ kp4, f16x8* __restrict__ w1h, f16x8* __restrict__ w2h,
    float4* __restrict__ xyz4, float4* __restrict__ cds4, int N, int M) {
    __shared__ __align__(16) char smem[16896];
    int pk = blockIdx.x, t = threadIdx.x;
    if (pk < 4) {
        tr4_tile((const float4*)Wq, qp4, 32, 128, 0, pk * 32, t, smem);
    } else if (pk < 8) {
        tr4_tile((const float4*)Wv, vp4, 32, 128, 0, (pk - 4) * 32, t, smem);
    } else if (pk < 12) {
        tr4_tile((const float4*)Wo, op4, 32, 128, 0, (pk - 8) * 32, t, smem);
    } else if (pk < 28) {
        // Wk pack: kp4[q*128+j] = {Wk[(4q+r)*128+j]}_{r=0..3}
        int idx = (pk - 12) * 256 + t;
        int q = idx >> 7, j = idx & 127;
        float4 w;
        w.x = Wk[(long)(4 * q + 0) * DIMF + j];
        w.y = Wk[(long)(4 * q + 1) * DIMF + j];
        w.z = Wk[(long)(4 * q + 2) * DIMF + j];
        w.w = Wk[(long)(4 * q + 3) * DIMF + j];
        kp4[q * DIMF + j] = w;
    } else if (pk < 92) {
        int idx = (pk - 28) * 256 + t;
        if (idx < N) {
            float x = xyz[3 * idx], y = xyz[3 * idx + 1], z = xyz[3 * idx + 2];
            xyz4[idx] = make_float4(x, y, z, (x * x + y * y) + z * z);
        }
    } else if (pk < 108) {
        int idx = (pk - 92) * 256 + t;
        if (idx < M) {
            int ic = idxc[idx];
            float cx = xyz[3 * ic], cy = xyz[3 * ic + 1], cz = xyz[3 * ic + 2];
            cds4[idx] = make_float4(-2.0f * cx, -2.0f * cy, -2.0f * cz,
                                    (cx * cx + cy * cy) + cz * cz);
        }
    } else if (pk < 140) {
        // w1h: B-frags of W1^T [128 x 512]; nt(32) x ks(4) x lane(64)
        int e = (pk - 108) * 256 + t;
        int l = e & 63, ks = (e >> 6) & 3, nt = e >> 8;
        int row = nt * 16 + (l & 15);
        int cb = ks * 32 + (l >> 4) * 8;
        const float* src = W1 + (long)row * DIMF + cb;
        f16x8 v;
#pragma unroll
        for (int j = 0; j < 8; ++j) v[j] = (_Float16)src[j];
        w1h[e] = v;
    } else {
        // w2h: B-frags of W2^T [512 x 128]; nt(8) x ks(16) x lane(64)
        int e = (pk - 140) * 256 + t;
        int l = e & 63, ks = (e >> 6) & 15, nt = e >> 10;
        int row = nt * 16 + (l & 15);
        int cb = ks * 32 + (l >> 4) * 8;
        const float* src = W2 + (long)row * (4 * DIMF) + cb;
        f16x8 v;
#pragma unroll
        for (int j = 0; j < 8; ++j) v[j] = (_Float16)src[j];
        w2h[e] = v;
    }
}

// ================= kernel 2: main — R6 structure + gather-phase ILP =========
// R9 post-mortem: per-wave restructure blew VGPR to 220 -> 1 block/CU -> 255us.
// Reverted to R6 (proven 100us main). Remaining stall is latency in the gather
// phases: D's k-loop was a DEPENDENT chain (LDS nbrl read -> global gather);
// manual 4-wide chunking puts 4 gathers in flight. C/phase-1/rank-select get
// unroll hints. launch_bounds(256,4) caps VGPR at 128 (4-block/CU cliff).
__global__ __launch_bounds__(256, 4) void main_kernel(
    const float4* __restrict__ xyz4, const float4* __restrict__ cds4g,
    const float* __restrict__ feats, const int* __restrict__ idxc,
    const float4* __restrict__ qp4, const float4* __restrict__ kp4,
    const float4* __restrict__ vp4, const float4* __restrict__ op4,
    const float* __restrict__ bo, const float* __restrict__ g1,
    const float* __restrict__ be1, const float* __restrict__ g2,
    const float* __restrict__ be2, const f16x8* __restrict__ w1h,
    const float* __restrict__ b1f, const f16x8* __restrict__ w2h,
    const float* __restrict__ b2f, float* __restrict__ cfin,
    int* __restrict__ bestm, int N, int M) {
    __shared__ __align__(16) char smem[32768];
    __shared__ int nbrl[CB][KNBR];
    __shared__ int cnt[CB];

    int t = threadIdx.x;
    int b = blockIdx.x;
    int nAttn = M / CB;

    if (b >= nAttn) {
        // ---------- nearest-center argmin, 32 pts/block, 8 lanes/pt ----------
        float4* cds = (float4*)smem;
        int pt = t >> 3, q = t & 7;
        int n = (b - nAttn) * PPB + pt;
        float4 p4 = xyz4[n];
        float px = p4.x, py = p4.y, pz = p4.z;
        float bd0 = INFINITY, bd1 = INFINITY;
        int bm0 = 0, bm1 = 0;
        for (int c0 = 0; c0 < M; c0 += 1024) {
            __syncthreads();
            for (int i = t; i < 1024; i += 256) cds[i] = cds4g[c0 + i];
            __syncthreads();
#pragma unroll 8
            for (int i = 0; i < 64; ++i) {
                int ci0 = q + (2 * i) * 8, ci1 = q + (2 * i + 1) * 8;
                float4 ca = cds[ci0];
                float4 cb = cds[ci1];
                float sa = fmaf(ca.x, px, fmaf(ca.y, py, fmaf(ca.z, pz, ca.w)));
                float sb = fmaf(cb.x, px, fmaf(cb.y, py, fmaf(cb.z, pz, cb.w)));
                if (sa < bd0) { bd0 = sa; bm0 = c0 + ci0; }
                if (sb < bd1) { bd1 = sb; bm1 = c0 + ci1; }
            }
        }
        if (bd1 < bd0 || (bd1 == bd0 && bm1 < bm0)) { bd0 = bd1; bm0 = bm1; }
#pragma unroll
        for (int o = 1; o < 8; o <<= 1) {
            float obd = __shfl_xor(bd0, o);
            int obm = __shfl_xor(bm0, o);
            if (obd < bd0 || (obd == bd0 && obm < bm0)) { bd0 = obd; bm0 = obm; }
        }
        if (q == 0) bestm[n] = bm0;
        return;
    }

    int m0 = b * CB;

    // ======== phase 1: radius top-K for centers m0..m0+7 ========
    {
        u64t(*cand)[CAND] = (u64t(*)[CAND])smem;
        if (t < CB) cnt[t] = 0;
        __syncthreads();
        float nx[CB], ny[CB], nz[CB], cw[CB];
#pragma unroll
        for (int tc = 0; tc < CB; ++tc) {
            float4 c4v = cds4g[m0 + tc];
            nx[tc] = c4v.x; ny[tc] = c4v.y; nz[tc] = c4v.z; cw[tc] = c4v.w;
        }
        const float R2 = RADIUS * RADIUS;
#pragma unroll 2
        for (int n = t; n < N; n += 256) {
            float4 p4 = xyz4[n];
            float rhs = R2 - p4.w;
#pragma unroll
            for (int tc = 0; tc < CB; ++tc) {
                float s = fmaf(nx[tc], p4.x, fmaf(ny[tc], p4.y, fmaf(nz[tc], p4.z, cw[tc])));
                if (s < rhs) {
                    int pos = atomicAdd(&cnt[tc], 1);
                    if (pos < CAND)
                        cand[tc][pos] = (((u64t)__float_as_uint(fmaxf(s + p4.w, 0.0f))) << 32) | (unsigned)n;
                }
            }
        }
        __syncthreads();
        int wv = t >> 6, lane = t & 63;
        for (int rep = 0; rep < 2; ++rep) {
            int cidx = wv + rep * 4;
            int C = cnt[cidx] < CAND ? cnt[cidx] : CAND;
            const u64t* vc = cand[cidx];
            if (C <= 64) {
                u64t mykey = (lane < C) ? vc[lane] : ~0ull;
                int rank = 0;
#pragma unroll 4
                for (int j = 0; j < C; ++j) rank += (vc[j] < mykey) ? 1 : 0;
                if (lane < C && rank < KNBR) nbrl[cidx][rank] = (int)(mykey & 0xffffffffu);
                if (lane >= C && lane < KNBR) nbrl[cidx][lane] = -1;
            } else {
                u64t mykey[4];
                int myrank[4];
#pragma unroll
                for (int s = 0; s < 4; ++s) {
                    int i = s * 64 + lane;
                    mykey[s] = (i < C) ? vc[i] : ~0ull;
                    myrank[s] = 0;
                }
#pragma unroll 4
                for (int j = 0; j < C; ++j) {
                    u64t kj = vc[j];
#pragma unroll
                    for (int s = 0; s < 4; ++s) myrank[s] += (kj < mykey[s]) ? 1 : 0;
                }
#pragma unroll
                for (int s = 0; s < 4; ++s) {
                    int i = s * 64 + lane;
                    if (i < C && myrank[s] < KNBR) nbrl[cidx][myrank[s]] = (int)(mykey[s] & 0xffffffffu);
                }
            }
        }
    }
    __syncthreads();  // cand reads done; smem becomes attn buffers

    // ======== phase 2: attention + FFN ========
    // LDS map: cf@0(4K), cf2@4096(4K), S1@8192(16K: qw -> pool -> hid f16),
    // S2@24576(4K: q -> updin -> cf2h f16), S3@28672(4K: softmax -> upd -> FFN out)
    float(*cf)[DIMF] = (float(*)[DIMF])smem;
    float(*cf2)[DIMF] = (float(*)[DIMF])(smem + 4096);
    float(*S1)[4 * DIMF] = (float(*)[4 * DIMF])(smem + 8192);
    float(*S2)[DIMF] = (float(*)[DIMF])(smem + 24576);
    float(*S3)[DIMF] = (float(*)[DIMF])(smem + 28672);

    int lane127 = t & 127;
    int cg = (t >> 7) * 4;
    int c8 = t >> 5, k32 = t & 31;

    {
        int ic = idxc[m0 + c8];
        *(float4*)&cf[c8][k32 * 4] = *(const float4*)&feats[(long)ic * DIMF + k32 * 4];
    }
    __syncthreads();

    // ---- A: q = Wq @ cf (scaled) -> S2 ----
    {
        float acc[4] = {0.f, 0.f, 0.f, 0.f};
#pragma unroll 2
        for (int jj = 0; jj < 32; ++jj) {
            float4 w = qp4[jj * DIMF + lane127];
#pragma unroll
            for (int cc = 0; cc < 4; ++cc) {
                float4 x = *(const float4*)&cf[cg + cc][jj * 4];
                acc[cc] += w.x * x.x + w.y * x.y + w.z * x.z + w.w * x.w;
            }
        }
#pragma unroll
        for (int cc = 0; cc < 4; ++cc) S2[cg + cc][lane127] = acc[cc] * 0.17677669529663687f;
    }
    __syncthreads();

    // ---- B: qw[c][h][j] -> S1 ----
    {
        int j = lane127, hs = t >> 7;
#pragma unroll
        for (int hh = 0; hh < 2; ++hh) {
            int h = hs * 2 + hh;
            float acc[8] = {0.f, 0.f, 0.f, 0.f, 0.f, 0.f, 0.f, 0.f};
            for (int d4 = 0; d4 < 8; ++d4) {
                float4 w = kp4[(h * 8 + d4) * DIMF + j];
#pragma unroll
                for (int c = 0; c < 8; ++c) {
                    float4 qv = *(const float4*)&S2[c][h * DH + d4 * 4];
                    acc[c] += qv.x * w.x + qv.y * w.y + qv.z * w.z + qv.w * w.w;
                }
            }
#pragma unroll
            for (int c = 0; c < 8; ++c) S1[c][h * DIMF + j] = acc[c];
        }
    }
    __syncthreads();

    // ---- C: logits + softmax -> S3 (unroll 4: 4 row-chunks in flight) ----
    {
        int ni = nbrl[c8][k32];
        const float* nrow = feats + (long)(ni < 0 ? 0 : ni) * DIMF;
        float lg[4] = {0.f, 0.f, 0.f, 0.f};
#pragma unroll 4
        for (int jj = 0; jj < 32; ++jj) {
            float4 f = *(const float4*)&nrow[jj * 4];
#pragma unroll
            for (int h = 0; h < 4; ++h) {
                float4 qwv = *(const float4*)&S1[c8][h * DIMF + jj * 4];
                lg[h] += f.x * qwv.x + f.y * qwv.y + f.z * qwv.z + f.w * qwv.w;
            }
        }
        if (ni < 0) { lg[0] = -1e9f; lg[1] = -1e9f; lg[2] = -1e9f; lg[3] = -1e9f; }
#pragma unroll
        for (int h = 0; h < 4; ++h) {
            float mx = lg[h];
            for (int o = 16; o; o >>= 1) mx = fmaxf(mx, __shfl_xor(mx, o, 32));
            float e = expf(lg[h] - mx);
            float s = e;
            for (int o = 16; o; o >>= 1) s += __shfl_xor(s, o, 32);
            S3[c8][h * KNBR + k32] = e / s;
        }
    }
    __syncthreads();

    // ---- D: pool -> S1 (manual 4-wide: break nbrl->gather dependent chain) --
    {
        int j4 = k32 * 4;
        float a0x = 0.f, a0y = 0.f, a0z = 0.f, a0w = 0.f;
        float a1x = 0.f, a1y = 0.f, a1z = 0.f, a1w = 0.f;
        float a2x = 0.f, a2y = 0.f, a2z = 0.f, a2w = 0.f;
        float a3x = 0.f, a3y = 0.f, a3z = 0.f, a3w = 0.f;
        for (int k = 0; k < KNBR; k += 4) {
            int na = nbrl[c8][k], nb = nbrl[c8][k + 1];
            int nc = nbrl[c8][k + 2], nd = nbrl[c8][k + 3];
            float4 fa = *(const float4*)&feats[(long)(na < 0 ? 0 : na) * DIMF + j4];
            float4 fb = *(const float4*)&feats[(long)(nb < 0 ? 0 : nb) * DIMF + j4];
            float4 fc = *(const float4*)&feats[(long)(nc < 0 ? 0 : nc) * DIMF + j4];
            float4 fd = *(const float4*)&feats[(long)(nd < 0 ? 0 : nd) * DIMF + j4];
            // same accumulation order as the scalar loop (k, k+1, k+2, k+3)
            {
                float w0 = S3[c8][0 * KNBR + k], w1 = S3[c8][1 * KNBR + k];
                float w2 = S3[c8][2 * KNBR + k], w3 = S3[c8][3 * KNBR + k];
                a0x += w0 * fa.x; a0y += w0 * fa.y; a0z += w0 * fa.z; a0w += w0 * fa.w;
                a1x += w1 * fa.x; a1y += w1 * fa.y; a1z += w1 * fa.z; a1w += w1 * fa.w;
                a2x += w2 * fa.x; a2y += w2 * fa.y; a2z += w2 * fa.z; a2w += w2 * fa.w;
                a3x += w3 * fa.x; a3y += w3 * fa.y; a3z += w3 * fa.z; a3w += w3 * fa.w;
            }
            {
                float w0 = S3[c8][0 * KNBR + k + 1], w1 = S3[c8][1 * KNBR + k + 1];
                float w2 = S3[c8][2 * KNBR + k + 1], w3 = S3[c8][3 * KNBR + k + 1];
                a0x += w0 * fb.x; a0y += w0 * fb.y; a0z += w0 * fb.z; a0w += w0 * fb.w;
                a1x += w1 * fb.x; a1y += w1 * fb.y; a1z += w1 * fb.z; a1w += w1 * fb.w;
                a2x += w2 * fb.x; a2y += w2 * fb.y; a2z += w2 * fb.z; a2w += w2 * fb.w;
                a3x += w3 * fb.x; a3y += w3 * fb.y; a3z += w3 * fb.z; a3w += w3 * fb.w;
            }
            {
                float w0 = S3[c8][0 * KNBR + k + 2], w1 = S3[c8][1 * KNBR + k + 2];
                float w2 = S3[c8][2 * KNBR + k + 2], w3 = S3[c8][3 * KNBR + k + 2];
                a0x += w0 * fc.x; a0y += w0 * fc.y; a0z += w0 * fc.z; a0w += w0 * fc.w;
                a1x += w1 * fc.x; a1y += w1 * fc.y; a1z += w1 * fc.z; a1w += w1 * fc.w;
                a2x += w2 * fc.x; a2y += w2 * fc.y; a2z += w2 * fc.z; a2w += w2 * fc.w;
                a3x += w3 * fc.x; a3y += w3 * fc.y; a3z += w3 * fc.z; a3w += w3 * fc.w;
            }
            {
                float w0 = S3[c8][0 * KNBR + k + 3], w1 = S3[c8][1 * KNBR + k + 3];
                float w2 = S3[c8][2 * KNBR + k + 3], w3 = S3[c8][3 * KNBR + k + 3];
                a0x += w0 * fd.x; a0y += w0 * fd.y; a0z += w0 * fd.z; a0w += w0 * fd.w;
                a1x += w1 * fd.x; a1y += w1 * fd.y; a1z += w1 * fd.z; a1w += w1 * fd.w;
                a2x += w2 * fd.x; a2y += w2 * fd.y; a2z += w2 * fd.z; a2w += w2 * fd.w;
                a3x += w3 * fd.x; a3y += w3 * fd.y; a3z += w3 * fd.z; a3w += w3 * fd.w;
            }
        }
        __syncthreads();
        *(float4*)&S1[c8][0 * DIMF + j4] = make_float4(a0x, a0y, a0z, a0w);
        *(float4*)&S1[c8][1 * DIMF + j4] = make_float4(a1x, a1y, a1z, a1w);
        *(float4*)&S1[c8][2 * DIMF + j4] = make_float4(a2x, a2y, a2z, a2w);
        *(float4*)&S1[c8][3 * DIMF + j4] = make_float4(a3x, a3y, a3z, a3w);
    }
    __syncthreads();

    // ---- E: updin -> S2 ----
    {
        int i = lane127, h = i >> 5, d = i & 31;
        float acc[4] = {0.f, 0.f, 0.f, 0.f};
#pragma unroll 2
        for (int jj = 0; jj < 32; ++jj) {
            float4 w = vp4[jj * DIMF + i];
#pragma unroll
            for (int cc = 0; cc < 4; ++cc) {
                float4 pv = *(const float4*)&S1[cg + cc][h * DIMF + jj * 4];
                acc[cc] += w.x * pv.x + w.y * pv.y + w.z * pv.z + w.w * pv.w;
            }
        }
        __syncthreads();
#pragma unroll
        for (int cc = 0; cc < 4; ++cc) S2[cg + cc][d * NH + h] = acc[cc];
    }
    __syncthreads();

    // ---- F: upd = Wo @ updin + bo -> S3 ----
    {
        int i = lane127;
        float acc[4] = {0.f, 0.f, 0.f, 0.f};
#pragma unroll 2
        for (int jj = 0; jj < 32; ++jj) {
            float4 w = op4[jj * DIMF + i];
#pragma unroll
            for (int cc = 0; cc < 4; ++cc) {
                float4 x = *(const float4*)&S2[cg + cc][jj * 4];
                acc[cc] += w.x * x.x + w.y * x.y + w.z * x.z + w.w * x.w;
            }
        }
        float b = bo[i];
        __syncthreads();
#pragma unroll
        for (int cc = 0; cc < 4; ++cc) S3[cg + cc][i] = acc[cc] + b;
    }
    __syncthreads();

    // ---- G: LN1 + residual -> cf2 (fp32) and cf2h (f16, S2 region, swizzled) ----
    {
        int i4 = k32 * 4;
        float4 u = *(const float4*)&S3[c8][i4];
        float s = ((u.x + u.y) + u.z) + u.w;
        for (int o = 16; o; o >>= 1) s += __shfl_xor(s, o, 32);
        float mu = s * (1.0f / DIMF);
        float d0 = u.x - mu, d1 = u.y - mu, d2 = u.z - mu, d3 = u.w - mu;
        float vs = ((d0 * d0 + d1 * d1) + d2 * d2) + d3 * d3;
        for (int o = 16; o; o >>= 1) vs += __shfl_xor(vs, o, 32);
        float rs = 1.0f / sqrtf(vs * (1.0f / DIMF) + 1e-5f);
        float4 g = *(const float4*)&g1[i4];
        float4 b = *(const float4*)&be1[i4];
        float4 base = *(const float4*)&cf[c8][i4];
        float4 r;
        r.x = base.x + d0 * rs * g.x + b.x;
        r.y = base.y + d1 * rs * g.y + b.y;
        r.z = base.z + d2 * rs * g.z + b.z;
        r.w = base.w + d3 * rs * g.w + b.w;
        *(float4*)&cf2[c8][i4] = r;
        {
            int byteoff = (c8 * 256 + i4 * 2) ^ ((c8 & 7) << 4);
            f16x4 hv = {(_Float16)r.x, (_Float16)r.y, (_Float16)r.z, (_Float16)r.w};
            *(f16x4*)(smem + 24576 + byteoff) = hv;
        }
    }
    __syncthreads();

    // ---- H: FFN1 via f16 MFMA: hid[16x512] = relu(cf2h @ W1^T + b1) -> S1 (f16) ----
    {
        int lane = t & 63, w = t >> 6;
        int la = lane & 15, kg = lane >> 4;
        f16x8 afr[4];
#pragma unroll
        for (int ks = 0; ks < 4; ++ks) {
            int byteoff = (la * 256 + ks * 64 + kg * 16) ^ ((la & 7) << 4);
            afr[ks] = *(const f16x8*)(smem + 24576 + byteoff);
        }
#pragma unroll
        for (int nt0 = 0; nt0 < 8; ++nt0) {
            int nt = w * 8 + nt0;
            f32x4 acc = {0.f, 0.f, 0.f, 0.f};
#pragma unroll
            for (int ks = 0; ks < 4; ++ks) {
                f16x8 bfr = w1h[(nt * 4 + ks) * 64 + lane];
                acc = __builtin_amdgcn_mfma_f32_16x16x32_f16(afr[ks], bfr, acc, 0, 0, 0);
            }
            int col = nt * 16 + la;
            float bb = b1f[col];
#pragma unroll
            for (int r = 0; r < 4; ++r) {
                int row = kg * 4 + r;
                float v = fmaxf(acc[r] + bb, 0.f);
                int byteoff = (row * 1024 + col * 2) ^ ((row & 7) << 4);
                *(_Float16*)(smem + 8192 + byteoff) = (_Float16)v;
            }
        }
    }
    __syncthreads();

    // ---- I: FFN2 via f16 MFMA: out[16x128] = hid @ W2^T + b2 -> S3 rows 0..7 ----
    {
        int lane = t & 63, w = t >> 6;
        int la = lane & 15, kg = lane >> 4;
        int nt0 = w * 2, nt1 = w * 2 + 1;
        f32x4 acc0 = {0.f, 0.f, 0.f, 0.f}, acc1 = {0.f, 0.f, 0.f, 0.f};
#pragma unroll
        for (int ks = 0; ks < 16; ++ks) {
            int byteoff = (la * 1024 + ks * 64 + kg * 16) ^ ((la & 7) << 4);
            f16x8 afr = *(const f16x8*)(smem + 8192 + byteoff);
            f16x8 b0 = w2h[(nt0 * 16 + ks) * 64 + lane];
            f16x8 b1v = w2h[(nt1 * 16 + ks) * 64 + lane];
            acc0 = __builtin_amdgcn_mfma_f32_16x16x32_f16(afr, b0, acc0, 0, 0, 0);
            acc1 = __builtin_amdgcn_mfma_f32_16x16x32_f16(afr, b1v, acc1, 0, 0, 0);
        }
        if (lane < 32) {  // rows 0..7 only
            float bb0 = b2f[nt0 * 16 + la];
            float bb1 = b2f[nt1 * 16 + la];
#pragma unroll
            for (int r = 0; r < 4; ++r) {
                int row = kg * 4 + r;
                S3[row][nt0 * 16 + la] = acc0[r] + bb0;
                S3[row][nt1 * 16 + la] = acc1[r] + bb1;
            }
        }
    }
    __syncthreads();

    // ---- J: LN2 + residual -> cfin ----
    {
        int i4 = k32 * 4;
        float4 u = *(const float4*)&S3[c8][i4];
        float s = ((u.x + u.y) + u.z) + u.w;
        for (int o = 16; o; o >>= 1) s += __shfl_xor(s, o, 32);
        float mu = s * (1.0f / DIMF);
        float d0 = u.x - mu, d1 = u.y - mu, d2 = u.z - mu, d3 = u.w - mu;
        float vs = ((d0 * d0 + d1 * d1) + d2 * d2) + d3 * d3;
        for (int o = 16; o; o >>= 1) vs += __shfl_xor(vs, o, 32);
        float rs = 1.0f / sqrtf(vs * (1.0f / DIMF) + 1e-5f);
        float4 g = *(const float4*)&g2[i4];
        float4 b = *(const float4*)&be2[i4];
        float4 base = *(const float4*)&cf2[c8][i4];
        float4 r;
        r.x = base.x + d0 * rs * g.x + b.x;
        r.y = base.y + d1 * rs * g.y + b.y;
        r.z = base.z + d2 * rs * g.z + b.z;
        r.w = base.w + d3 * rs * g.w + b.w;
        *(float4*)&cfin[(long)(m0 + c8) * DIMF + i4] = r;
    }
}

// ================= kernel 3: out = feats + cfin[bestm] ======================
__global__ __launch_bounds__(256) void out_kernel(const float4* __restrict__ feats4,
                                                  const float* __restrict__ cfin,
                                                  const int* __restrict__ bestm,
                                                  float4* __restrict__ out4, int total) {
    int idx = blockIdx.x * 256 + threadIdx.x;
    if (idx >= total) return;
    int n = idx >> 5, c = idx & 31;
    const float4* cf4 = (const float4*)cfin;
    float4 f = feats4[idx];
    float4 g = cf4[(long)bestm[n] * 32 + c];
    out4[idx] = make_float4(f.x + g.x, f.y + g.y, f.z + g.z, f.w + g.w);
}

extern "C" void kernel_launch(void* const* d_in, const int* in_sizes, int n_in,
                              void* d_out, int out_size, void* d_ws, size_t ws_size,
                              hipStream_t stream) {
    const float* xyz = (const float*)d_in[0];
    const float* feats = (const float*)d_in[1];
    const int* idxc = (const int*)d_in[2];
    const float* Wq = (const float*)d_in[3];
    const float* Wk = (const float*)d_in[4];
    const float* Wv = (const float*)d_in[5];
    const float* Wo = (const float*)d_in[6];
    const float* bo = (const float*)d_in[7];
    const float* g1 = (const float*)d_in[8];
    const float* be1 = (const float*)d_in[9];
    const float* g2 = (const float*)d_in[10];
    const float* be2 = (const float*)d_in[11];
    const float* W1 = (const float*)d_in[12];
    const float* b1f = (const float*)d_in[13];
    const float* W2 = (const float*)d_in[14];
    const float* b2f = (const float*)d_in[15];

    int N = in_sizes[0] / 3;
    int M = in_sizes[2];

    char* ws = (char*)d_ws;
    size_t off = 0;
    float* cfin = (float*)(ws + off); off += (size_t)M * DIMF * 4;
    int* bestm = (int*)(ws + off); off += (size_t)N * 4;
    float4* qp4 = (float4*)(ws + off); off += (size_t)DIMF * DIMF * 4;
    float4* vp4 = (float4*)(ws + off); off += (size_t)DIMF * DIMF * 4;
    float4* op4 = (float4*)(ws + off); off += (size_t)DIMF * DIMF * 4;
    float4* kp4 = (float4*)(ws + off); off += (size_t)DIMF * DIMF * 4;
    f16x8* w1h = (f16x8*)(ws + off); off += (size_t)8192 * 16;
    f16x8* w2h = (f16x8*)(ws + off); off += (size_t)8192 * 16;
    float4* xyz4 = (float4*)(ws + off); off += (size_t)N * 16;
    float4* cds4 = (float4*)(ws + off); off += (size_t)M * 16;
    (void)ws_size; (void)n_in; (void)out_size;

    pack_kernel<<<PACK_BLOCKS, 256, 0, stream>>>(
        xyz, idxc, Wq, Wv, Wo, W1, W2, Wk,
        qp4, vp4, op4, kp4, w1h, w2h, xyz4, cds4, N, M);
    main_kernel<<<M / CB + N / PPB, 256, 0, stream>>>(
        xyz4, cds4, feats, idxc, qp4, kp4, vp4, op4, bo, g1, be1, g2, be2,
        w1h, b1f, w2h, b2f, cfin, bestm, N, M);
    out_kernel<<<(N * DIMF / 4 + 255) / 256, 256, 0, stream>>>(
        (const float4*)feats, cfin, bestm, (float4*)d_out, N * DIMF / 4);
}

// Round 11
// 171.539 us; speedup vs baseline: 2.0016x; 1.0160x over previous
//
#include <hip/hip_runtime.h>
#include <hip/hip_bf16.h>

#define DIMF 128
#define KNBR 32
#define NH 4
#define DH 32
#define RADIUS 0.3f
#define CB 8       // centers per attn block (R6 best-known structure)
#define CAND 256   // max candidates/center (Poisson max lambda~118)
#define PPB 32     // points per argmin block

#define PACK_BLOCKS 172    // 12 tr4 + 16 Wk + 64 xyz4 + 16 cds4 + 32 w1h + 32 w2h

typedef unsigned long long u64t;
typedef _Float16 f16x8 __attribute__((ext_vector_type(8)));
typedef _Float16 f16x4 __attribute__((ext_vector_type(4)));
typedef float f32x4 __attribute__((ext_vector_type(4)));

// float4-granular transpose tile: out4[a*BI + b] = in4[b*AI + a]
__device__ __forceinline__ void tr4_tile(const float4* __restrict__ in4, float4* __restrict__ out4,
                                         int AI, int BI, int a0, int b0, int t, char* smem) {
    float4(*tile)[33] = (float4(*)[33])smem;
    int tx = t & 31, ty = t >> 5;  // 32 x 8
    for (int r = ty; r < 32; r += 8) tile[r][tx] = in4[(long)(b0 + r) * AI + a0 + tx];
    __syncthreads();
    for (int r = ty; r < 32; r += 8) out4[(long)(a0 + r) * BI + b0 + tx] = tile[tx][r];
}

// ====== kernel 1: weight packs + xyz4/cds4 + f16 MFMA weight packs (R6) =====
__global__ __launch_bounds__(256) void pack_kernel(
    const float* __restrict__ xyz, const int* __restrict__ idxc,
    const float* __restrict__ Wq, const float* __restrict__ Wv,
    const float* __restrict__ Wo, const float* __restrict__ W1,
    const float* __restrict__ W2, const float* __restrict__ Wk,
    float4* __restrict__ qp4, float4* __restrict__ vp4, float4* __restrict__ op4,
    float4* __restrict__ kp4, f16x8* __restrict__ w1h, f16x8* __restrict__ w2h,
    float4* __restrict__ xyz4, float4* __restrict__ cds4, int N, int M) {
    __shared__ __align__(16) char smem[16896];
    int pk = blockIdx.x, t = threadIdx.x;
    if (pk < 4) {
        tr4_tile((const float4*)Wq, qp4, 32, 128, 0, pk * 32, t, smem);
    } else if (pk < 8) {
        tr4_tile((const float4*)Wv, vp4, 32, 128, 0, (pk - 4) * 32, t, smem);
    } else if (pk < 12) {
        tr4_tile((const float4*)Wo, op4, 32, 128, 0, (pk - 8) * 32, t, smem);
    } else if (pk < 28) {
        // Wk pack: kp4[q*128+j] = {Wk[(4q+r)*128+j]}_{r=0..3}
        int idx = (pk - 12) * 256 + t;
        int q = idx >> 7, j = idx & 127;
        float4 w;
        w.x = Wk[(long)(4 * q + 0) * DIMF + j];
        w.y = Wk[(long)(4 * q + 1) * DIMF + j];
        w.z = Wk[(long)(4 * q + 2) * DIMF + j];
        w.w = Wk[(long)(4 * q + 3) * DIMF + j];
        kp4[q * DIMF + j] = w;
    } else if (pk < 92) {
        int idx = (pk - 28) * 256 + t;
        if (idx < N) {
            float x = xyz[3 * idx], y = xyz[3 * idx + 1], z = xyz[3 * idx + 2];
            xyz4[idx] = make_float4(x, y, z, (x * x + y * y) + z * z);
        }
    } else if (pk < 108) {
        int idx = (pk - 92) * 256 + t;
        if (idx < M) {
            int ic = idxc[idx];
            float cx = xyz[3 * ic], cy = xyz[3 * ic + 1], cz = xyz[3 * ic + 2];
            cds4[idx] = make_float4(-2.0f * cx, -2.0f * cy, -2.0f * cz,
                                    (cx * cx + cy * cy) + cz * cz);
        }
    } else if (pk < 140) {
        // w1h: B-frags of W1^T [128 x 512]; nt(32) x ks(4) x lane(64)
        int e = (pk - 108) * 256 + t;
        int l = e & 63, ks = (e >> 6) & 3, nt = e >> 8;
        int row = nt * 16 + (l & 15);
        int cb = ks * 32 + (l >> 4) * 8;
        const float* src = W1 + (long)row * DIMF + cb;
        f16x8 v;
#pragma unroll
        for (int j = 0; j < 8; ++j) v[j] = (_Float16)src[j];
        w1h[e] = v;
    } else {
        // w2h: B-frags of W2^T [512 x 128]; nt(8) x ks(16) x lane(64)
        int e = (pk - 140) * 256 + t;
        int l = e & 63, ks = (e >> 6) & 15, nt = e >> 10;
        int row = nt * 16 + (l & 15);
        int cb = ks * 32 + (l >> 4) * 8;
        const float* src = W2 + (long)row * (4 * DIMF) + cb;
        f16x8 v;
#pragma unroll
        for (int j = 0; j < 8; ++j) v[j] = (_Float16)src[j];
        w2h[e] = v;
    }
}

// ================= kernel 2: main — R10 structure, deeper gather ILP ========
// R10 confirmed gather latency is the stall: D 4-wide took main 100->84us.
// This round: D 8-wide (8 gathers in flight, same accumulation order), C
// unroll 8, argmin 4 min-streams (halved serial cmp chain; lexicographic
// (s,idx) merges preserve np.argmin first-occurrence). All bit-identical.
__global__ __launch_bounds__(256, 4) void main_kernel(
    const float4* __restrict__ xyz4, const float4* __restrict__ cds4g,
    const float* __restrict__ feats, const int* __restrict__ idxc,
    const float4* __restrict__ qp4, const float4* __restrict__ kp4,
    const float4* __restrict__ vp4, const float4* __restrict__ op4,
    const float* __restrict__ bo, const float* __restrict__ g1,
    const float* __restrict__ be1, const float* __restrict__ g2,
    const float* __restrict__ be2, const f16x8* __restrict__ w1h,
    const float* __restrict__ b1f, const f16x8* __restrict__ w2h,
    const float* __restrict__ b2f, float* __restrict__ cfin,
    int* __restrict__ bestm, int N, int M) {
    __shared__ __align__(16) char smem[32768];
    __shared__ int nbrl[CB][KNBR];
    __shared__ int cnt[CB];

    int t = threadIdx.x;
    int b = blockIdx.x;
    int nAttn = M / CB;

    if (b >= nAttn) {
        // ---------- nearest-center argmin, 32 pts/block, 8 lanes/pt ----------
        // 4 independent min-streams (stream j: indices congruent j mod 4,
        // ascending within stream -> strict < keeps lowest index).
        float4* cds = (float4*)smem;
        int pt = t >> 3, q = t & 7;
        int n = (b - nAttn) * PPB + pt;
        float4 p4 = xyz4[n];
        float px = p4.x, py = p4.y, pz = p4.z;
        float bd0 = INFINITY, bd1 = INFINITY, bd2 = INFINITY, bd3 = INFINITY;
        int bm0 = 0, bm1 = 0, bm2 = 0, bm3 = 0;
        for (int c0 = 0; c0 < M; c0 += 1024) {
            __syncthreads();
            for (int i = t; i < 1024; i += 256) cds[i] = cds4g[c0 + i];
            __syncthreads();
#pragma unroll 8
            for (int i = 0; i < 32; ++i) {
                int ci0 = q + (4 * i) * 8, ci1 = q + (4 * i + 1) * 8;
                int ci2 = q + (4 * i + 2) * 8, ci3 = q + (4 * i + 3) * 8;
                float4 ca = cds[ci0];
                float4 cb = cds[ci1];
                float4 cc = cds[ci2];
                float4 cd = cds[ci3];
                float sa = fmaf(ca.x, px, fmaf(ca.y, py, fmaf(ca.z, pz, ca.w)));
                float sb = fmaf(cb.x, px, fmaf(cb.y, py, fmaf(cb.z, pz, cb.w)));
                float sc = fmaf(cc.x, px, fmaf(cc.y, py, fmaf(cc.z, pz, cc.w)));
                float sd = fmaf(cd.x, px, fmaf(cd.y, py, fmaf(cd.z, pz, cd.w)));
                if (sa < bd0) { bd0 = sa; bm0 = c0 + ci0; }
                if (sb < bd1) { bd1 = sb; bm1 = c0 + ci1; }
                if (sc < bd2) { bd2 = sc; bm2 = c0 + ci2; }
                if (sd < bd3) { bd3 = sd; bm3 = c0 + ci3; }
            }
        }
        // lexicographic (s, index) merges — exact np.argmin semantics
        if (bd1 < bd0 || (bd1 == bd0 && bm1 < bm0)) { bd0 = bd1; bm0 = bm1; }
        if (bd3 < bd2 || (bd3 == bd2 && bm3 < bm2)) { bd2 = bd3; bm2 = bm3; }
        if (bd2 < bd0 || (bd2 == bd0 && bm2 < bm0)) { bd0 = bd2; bm0 = bm2; }
#pragma unroll
        for (int o = 1; o < 8; o <<= 1) {
            float obd = __shfl_xor(bd0, o);
            int obm = __shfl_xor(bm0, o);
            if (obd < bd0 || (obd == bd0 && obm < bm0)) { bd0 = obd; bm0 = obm; }
        }
        if (q == 0) bestm[n] = bm0;
        return;
    }

    int m0 = b * CB;

    // ======== phase 1: radius top-K for centers m0..m0+7 ========
    {
        u64t(*cand)[CAND] = (u64t(*)[CAND])smem;
        if (t < CB) cnt[t] = 0;
        __syncthreads();
        float nx[CB], ny[CB], nz[CB], cw[CB];
#pragma unroll
        for (int tc = 0; tc < CB; ++tc) {
            float4 c4v = cds4g[m0 + tc];
            nx[tc] = c4v.x; ny[tc] = c4v.y; nz[tc] = c4v.z; cw[tc] = c4v.w;
        }
        const float R2 = RADIUS * RADIUS;
#pragma unroll 2
        for (int n = t; n < N; n += 256) {
            float4 p4 = xyz4[n];
            float rhs = R2 - p4.w;
#pragma unroll
            for (int tc = 0; tc < CB; ++tc) {
                float s = fmaf(nx[tc], p4.x, fmaf(ny[tc], p4.y, fmaf(nz[tc], p4.z, cw[tc])));
                if (s < rhs) {
                    int pos = atomicAdd(&cnt[tc], 1);
                    if (pos < CAND)
                        cand[tc][pos] = (((u64t)__float_as_uint(fmaxf(s + p4.w, 0.0f))) << 32) | (unsigned)n;
                }
            }
        }
        __syncthreads();
        int wv = t >> 6, lane = t & 63;
        for (int rep = 0; rep < 2; ++rep) {
            int cidx = wv + rep * 4;
            int C = cnt[cidx] < CAND ? cnt[cidx] : CAND;
            const u64t* vc = cand[cidx];
            if (C <= 64) {
                u64t mykey = (lane < C) ? vc[lane] : ~0ull;
                int rank = 0;
#pragma unroll 4
                for (int j = 0; j < C; ++j) rank += (vc[j] < mykey) ? 1 : 0;
                if (lane < C && rank < KNBR) nbrl[cidx][rank] = (int)(mykey & 0xffffffffu);
                if (lane >= C && lane < KNBR) nbrl[cidx][lane] = -1;
            } else {
                u64t mykey[4];
                int myrank[4];
#pragma unroll
                for (int s = 0; s < 4; ++s) {
                    int i = s * 64 + lane;
                    mykey[s] = (i < C) ? vc[i] : ~0ull;
                    myrank[s] = 0;
                }
#pragma unroll 4
                for (int j = 0; j < C; ++j) {
                    u64t kj = vc[j];
#pragma unroll
                    for (int s = 0; s < 4; ++s) myrank[s] += (kj < mykey[s]) ? 1 : 0;
                }
#pragma unroll
                for (int s = 0; s < 4; ++s) {
                    int i = s * 64 + lane;
                    if (i < C && myrank[s] < KNBR) nbrl[cidx][myrank[s]] = (int)(mykey[s] & 0xffffffffu);
                }
            }
        }
    }
    __syncthreads();  // cand reads done; smem becomes attn buffers

    // ======== phase 2: attention + FFN ========
    // LDS map: cf@0(4K), cf2@4096(4K), S1@8192(16K: qw -> pool -> hid f16),
    // S2@24576(4K: q -> updin -> cf2h f16), S3@28672(4K: softmax -> upd -> FFN out)
    float(*cf)[DIMF] = (float(*)[DIMF])smem;
    float(*cf2)[DIMF] = (float(*)[DIMF])(smem + 4096);
    float(*S1)[4 * DIMF] = (float(*)[4 * DIMF])(smem + 8192);
    float(*S2)[DIMF] = (float(*)[DIMF])(smem + 24576);
    float(*S3)[DIMF] = (float(*)[DIMF])(smem + 28672);

    int lane127 = t & 127;
    int cg = (t >> 7) * 4;
    int c8 = t >> 5, k32 = t & 31;

    {
        int ic = idxc[m0 + c8];
        *(float4*)&cf[c8][k32 * 4] = *(const float4*)&feats[(long)ic * DIMF + k32 * 4];
    }
    __syncthreads();

    // ---- A: q = Wq @ cf (scaled) -> S2 ----
    {
        float acc[4] = {0.f, 0.f, 0.f, 0.f};
#pragma unroll 2
        for (int jj = 0; jj < 32; ++jj) {
            float4 w = qp4[jj * DIMF + lane127];
#pragma unroll
            for (int cc = 0; cc < 4; ++cc) {
                float4 x = *(const float4*)&cf[cg + cc][jj * 4];
                acc[cc] += w.x * x.x + w.y * x.y + w.z * x.z + w.w * x.w;
            }
        }
#pragma unroll
        for (int cc = 0; cc < 4; ++cc) S2[cg + cc][lane127] = acc[cc] * 0.17677669529663687f;
    }
    __syncthreads();

    // ---- B: qw[c][h][j] -> S1 ----
    {
        int j = lane127, hs = t >> 7;
#pragma unroll
        for (int hh = 0; hh < 2; ++hh) {
            int h = hs * 2 + hh;
            float acc[8] = {0.f, 0.f, 0.f, 0.f, 0.f, 0.f, 0.f, 0.f};
            for (int d4 = 0; d4 < 8; ++d4) {
                float4 w = kp4[(h * 8 + d4) * DIMF + j];
#pragma unroll
                for (int c = 0; c < 8; ++c) {
                    float4 qv = *(const float4*)&S2[c][h * DH + d4 * 4];
                    acc[c] += qv.x * w.x + qv.y * w.y + qv.z * w.z + qv.w * w.w;
                }
            }
#pragma unroll
            for (int c = 0; c < 8; ++c) S1[c][h * DIMF + j] = acc[c];
        }
    }
    __syncthreads();

    // ---- C: logits + softmax -> S3 (unroll 8: 8 row-chunks in flight) ----
    {
        int ni = nbrl[c8][k32];
        const float* nrow = feats + (long)(ni < 0 ? 0 : ni) * DIMF;
        float lg[4] = {0.f, 0.f, 0.f, 0.f};
#pragma unroll 8
        for (int jj = 0; jj < 32; ++jj) {
            float4 f = *(const float4*)&nrow[jj * 4];
#pragma unroll
            for (int h = 0; h < 4; ++h) {
                float4 qwv = *(const float4*)&S1[c8][h * DIMF + jj * 4];
                lg[h] += f.x * qwv.x + f.y * qwv.y + f.z * qwv.z + f.w * qwv.w;
            }
        }
        if (ni < 0) { lg[0] = -1e9f; lg[1] = -1e9f; lg[2] = -1e9f; lg[3] = -1e9f; }
#pragma unroll
        for (int h = 0; h < 4; ++h) {
            float mx = lg[h];
            for (int o = 16; o; o >>= 1) mx = fmaxf(mx, __shfl_xor(mx, o, 32));
            float e = expf(lg[h] - mx);
            float s = e;
            for (int o = 16; o; o >>= 1) s += __shfl_xor(s, o, 32);
            S3[c8][h * KNBR + k32] = e / s;
        }
    }
    __syncthreads();

    // ---- D: pool -> S1 (8-wide: 8 gathers in flight; accumulation order
    //         preserved exactly: k, k+1, ..., k+7 sequential) ----
    {
        int j4 = k32 * 4;
        float a0x = 0.f, a0y = 0.f, a0z = 0.f, a0w = 0.f;
        float a1x = 0.f, a1y = 0.f, a1z = 0.f, a1w = 0.f;
        float a2x = 0.f, a2y = 0.f, a2z = 0.f, a2w = 0.f;
        float a3x = 0.f, a3y = 0.f, a3z = 0.f, a3w = 0.f;
        for (int k = 0; k < KNBR; k += 8) {
            int ni[8];
            float4 fv[8];
#pragma unroll
            for (int s = 0; s < 8; ++s) ni[s] = nbrl[c8][k + s];
#pragma unroll
            for (int s = 0; s < 8; ++s)
                fv[s] = *(const float4*)&feats[(long)(ni[s] < 0 ? 0 : ni[s]) * DIMF + j4];
#pragma unroll
            for (int s = 0; s < 8; ++s) {
                float w0 = S3[c8][0 * KNBR + k + s], w1 = S3[c8][1 * KNBR + k + s];
                float w2 = S3[c8][2 * KNBR + k + s], w3 = S3[c8][3 * KNBR + k + s];
                float4 f = fv[s];
                a0x += w0 * f.x; a0y += w0 * f.y; a0z += w0 * f.z; a0w += w0 * f.w;
                a1x += w1 * f.x; a1y += w1 * f.y; a1z += w1 * f.z; a1w += w1 * f.w;
                a2x += w2 * f.x; a2y += w2 * f.y; a2z += w2 * f.z; a2w += w2 * f.w;
                a3x += w3 * f.x; a3y += w3 * f.y; a3z += w3 * f.z; a3w += w3 * f.w;
            }
        }
        __syncthreads();
        *(float4*)&S1[c8][0 * DIMF + j4] = make_float4(a0x, a0y, a0z, a0w);
        *(float4*)&S1[c8][1 * DIMF + j4] = make_float4(a1x, a1y, a1z, a1w);
        *(float4*)&S1[c8][2 * DIMF + j4] = make_float4(a2x, a2y, a2z, a2w);
        *(float4*)&S1[c8][3 * DIMF + j4] = make_float4(a3x, a3y, a3z, a3w);
    }
    __syncthreads();

    // ---- E: updin -> S2 ----
    {
        int i = lane127, h = i >> 5, d = i & 31;
        float acc[4] = {0.f, 0.f, 0.f, 0.f};
#pragma unroll 2
        for (int jj = 0; jj < 32; ++jj) {
            float4 w = vp4[jj * DIMF + i];
#pragma unroll
            for (int cc = 0; cc < 4; ++cc) {
                float4 pv = *(const float4*)&S1[cg + cc][h * DIMF + jj * 4];
                acc[cc] += w.x * pv.x + w.y * pv.y + w.z * pv.z + w.w * pv.w;
            }
        }
        __syncthreads();
#pragma unroll
        for (int cc = 0; cc < 4; ++cc) S2[cg + cc][d * NH + h] = acc[cc];
    }
    __syncthreads();

    // ---- F: upd = Wo @ updin + bo -> S3 ----
    {
        int i = lane127;
        float acc[4] = {0.f, 0.f, 0.f, 0.f};
#pragma unroll 2
        for (int jj = 0; jj < 32; ++jj) {
            float4 w = op4[jj * DIMF + i];
#pragma unroll
            for (int cc = 0; cc < 4; ++cc) {
                float4 x = *(const float4*)&S2[cg + cc][jj * 4];
                acc[cc] += w.x * x.x + w.y * x.y + w.z * x.z + w.w * x.w;
            }
        }
        float b = bo[i];
        __syncthreads();
#pragma unroll
        for (int cc = 0; cc < 4; ++cc) S3[cg + cc][i] = acc[cc] + b;
    }
    __syncthreads();

    // ---- G: LN1 + residual -> cf2 (fp32) and cf2h (f16, S2 region, swizzled) ----
    {
        int i4 = k32 * 4;
        float4 u = *(const float4*)&S3[c8][i4];
        float s = ((u.x + u.y) + u.z) + u.w;
        for (int o = 16; o; o >>= 1) s += __shfl_xor(s, o, 32);
        float mu = s * (1.0f / DIMF);
        float d0 = u.x - mu, d1 = u.y - mu, d2 = u.z - mu, d3 = u.w - mu;
        float vs = ((d0 * d0 + d1 * d1) + d2 * d2) + d3 * d3;
        for (int o = 16; o; o >>= 1) vs += __shfl_xor(vs, o, 32);
        float rs = 1.0f / sqrtf(vs * (1.0f / DIMF) + 1e-5f);
        float4 g = *(const float4*)&g1[i4];
        float4 b = *(const float4*)&be1[i4];
        float4 base = *(const float4*)&cf[c8][i4];
        float4 r;
        r.x = base.x + d0 * rs * g.x + b.x;
        r.y = base.y + d1 * rs * g.y + b.y;
        r.z = base.z + d2 * rs * g.z + b.z;
        r.w = base.w + d3 * rs * g.w + b.w;
        *(float4*)&cf2[c8][i4] = r;
        {
            int byteoff = (c8 * 256 + i4 * 2) ^ ((c8 & 7) << 4);
            f16x4 hv = {(_Float16)r.x, (_Float16)r.y, (_Float16)r.z, (_Float16)r.w};
            *(f16x4*)(smem + 24576 + byteoff) = hv;
        }
    }
    __syncthreads();

    // ---- H: FFN1 via f16 MFMA: hid[16x512] = relu(cf2h @ W1^T + b1) -> S1 (f16) ----
    {
        int lane = t & 63, w = t >> 6;
        int la = lane & 15, kg = lane >> 4;
        f16x8 afr[4];
#pragma unroll
        for (int ks = 0; ks < 4; ++ks) {
            int byteoff = (la * 256 + ks * 64 + kg * 16) ^ ((la & 7) << 4);
            afr[ks] = *(const f16x8*)(smem + 24576 + byteoff);
        }
#pragma unroll
        for (int nt0 = 0; nt0 < 8; ++nt0) {
            int nt = w * 8 + nt0;
            f32x4 acc = {0.f, 0.f, 0.f, 0.f};
#pragma unroll
            for (int ks = 0; ks < 4; ++ks) {
                f16x8 bfr = w1h[(nt * 4 + ks) * 64 + lane];
                acc = __builtin_amdgcn_mfma_f32_16x16x32_f16(afr[ks], bfr, acc, 0, 0, 0);
            }
            int col = nt * 16 + la;
            float bb = b1f[col];
#pragma unroll
            for (int r = 0; r < 4; ++r) {
                int row = kg * 4 + r;
                float v = fmaxf(acc[r] + bb, 0.f);
                int byteoff = (row * 1024 + col * 2) ^ ((row & 7) << 4);
                *(_Float16*)(smem + 8192 + byteoff) = (_Float16)v;
            }
        }
    }
    __syncthreads();

    // ---- I: FFN2 via f16 MFMA: out[16x128] = hid @ W2^T + b2 -> S3 rows 0..7 ----
    {
        int lane = t & 63, w = t >> 6;
        int la = lane & 15, kg = lane >> 4;
        int nt0 = w * 2, nt1 = w * 2 + 1;
        f32x4 acc0 = {0.f, 0.f, 0.f, 0.f}, acc1 = {0.f, 0.f, 0.f, 0.f};
#pragma unroll
        for (int ks = 0; ks < 16; ++ks) {
            int byteoff = (la * 1024 + ks * 64 + kg * 16) ^ ((la & 7) << 4);
            f16x8 afr = *(const f16x8*)(smem + 8192 + byteoff);
            f16x8 b0 = w2h[(nt0 * 16 + ks) * 64 + lane];
            f16x8 b1v = w2h[(nt1 * 16 + ks) * 64 + lane];
            acc0 = __builtin_amdgcn_mfma_f32_16x16x32_f16(afr, b0, acc0, 0, 0, 0);
            acc1 = __builtin_amdgcn_mfma_f32_16x16x32_f16(afr, b1v, acc1, 0, 0, 0);
        }
        if (lane < 32) {  // rows 0..7 only
            float bb0 = b2f[nt0 * 16 + la];
            float bb1 = b2f[nt1 * 16 + la];
#pragma unroll
            for (int r = 0; r < 4; ++r) {
                int row = kg * 4 + r;
                S3[row][nt0 * 16 + la] = acc0[r] + bb0;
                S3[row][nt1 * 16 + la] = acc1[r] + bb1;
            }
        }
    }
    __syncthreads();

    // ---- J: LN2 + residual -> cfin ----
    {
        int i4 = k32 * 4;
        float4 u = *(const float4*)&S3[c8][i4];
        float s = ((u.x + u.y) + u.z) + u.w;
        for (int o = 16; o; o >>= 1) s += __shfl_xor(s, o, 32);
        float mu = s * (1.0f / DIMF);
        float d0 = u.x - mu, d1 = u.y - mu, d2 = u.z - mu, d3 = u.w - mu;
        float vs = ((d0 * d0 + d1 * d1) + d2 * d2) + d3 * d3;
        for (int o = 16; o; o >>= 1) vs += __shfl_xor(vs, o, 32);
        float rs = 1.0f / sqrtf(vs * (1.0f / DIMF) + 1e-5f);
        float4 g = *(const float4*)&g2[i4];
        float4 b = *(const float4*)&be2[i4];
        float4 base = *(const float4*)&cf2[c8][i4];
        float4 r;
        r.x = base.x + d0 * rs * g.x + b.x;
        r.y = base.y + d1 * rs * g.y + b.y;
        r.z = base.z + d2 * rs * g.z + b.z;
        r.w = base.w + d3 * rs * g.w + b.w;
        *(float4*)&cfin[(long)(m0 + c8) * DIMF + i4] = r;
    }
}

// ================= kernel 3: out = feats + cfin[bestm] ======================
__global__ __launch_bounds__(256) void out_kernel(const float4* __restrict__ feats4,
                                                  const float* __restrict__ cfin,
                                                  const int* __restrict__ bestm,
                                                  float4* __restrict__ out4, int total) {
    int idx = blockIdx.x * 256 + threadIdx.x;
    if (idx >= total) return;
    int n = idx >> 5, c = idx & 31;
    const float4* cf4 = (const float4*)cfin;
    float4 f = feats4[idx];
    float4 g = cf4[(long)bestm[n] * 32 + c];
    out4[idx] = make_float4(f.x + g.x, f.y + g.y, f.z + g.z, f.w + g.w);
}

extern "C" void kernel_launch(void* const* d_in, const int* in_sizes, int n_in,
                              void* d_out, int out_size, void* d_ws, size_t ws_size,
                              hipStream_t stream) {
    const float* xyz = (const float*)d_in[0];
    const float* feats = (const float*)d_in[1];
    const int* idxc = (const int*)d_in[2];
    const float* Wq = (const float*)d_in[3];
    const float* Wk = (const float*)d_in[4];
    const float* Wv = (const float*)d_in[5];
    const float* Wo = (const float*)d_in[6];
    const float* bo = (const float*)d_in[7];
    const float* g1 = (const float*)d_in[8];
    const float* be1 = (const float*)d_in[9];
    const float* g2 = (const float*)d_in[10];
    const float* be2 = (const float*)d_in[11];
    const float* W1 = (const float*)d_in[12];
    const float* b1f = (const float*)d_in[13];
    const float* W2 = (const float*)d_in[14];
    const float* b2f = (const float*)d_in[15];

    int N = in_sizes[0] / 3;
    int M = in_sizes[2];

    char* ws = (char*)d_ws;
    size_t off = 0;
    float* cfin = (float*)(ws + off); off += (size_t)M * DIMF * 4;
    int* bestm = (int*)(ws + off); off += (size_t)N * 4;
    float4* qp4 = (float4*)(ws + off); off += (size_t)DIMF * DIMF * 4;
    float4* vp4 = (float4*)(ws + off); off += (size_t)DIMF * DIMF * 4;
    float4* op4 = (float4*)(ws + off); off += (size_t)DIMF * DIMF * 4;
    float4* kp4 = (float4*)(ws + off); off += (size_t)DIMF * DIMF * 4;
    f16x8* w1h = (f16x8*)(ws + off); off += (size_t)8192 * 16;
    f16x8* w2h = (f16x8*)(ws + off); off += (size_t)8192 * 16;
    float4* xyz4 = (float4*)(ws + off); off += (size_t)N * 16;
    float4* cds4 = (float4*)(ws + off); off += (size_t)M * 16;
    (void)ws_size; (void)n_in; (void)out_size;

    pack_kernel<<<PACK_BLOCKS, 256, 0, stream>>>(
        xyz, idxc, Wq, Wv, Wo, W1, W2, Wk,
        qp4, vp4, op4, kp4, w1h, w2h, xyz4, cds4, N, M);
    main_kernel<<<M / CB + N / PPB, 256, 0, stream>>>(
        xyz4, cds4, feats, idxc, qp4, kp4, vp4, op4, bo, g1, be1, g2, be2,
        w1h, b1f, w2h, b2f, cfin, bestm, N, M);
    out_kernel<<<(N * DIMF / 4 + 255) / 256, 256, 0, stream>>>(
        (const float4*)feats, cfin, bestm, (float4*)d_out, N * DIMF / 4);
}